// Round 15
// baseline (602.728 us; speedup 1.0000x reference)
//
#include <hip/hip_runtime.h>
#include <hip/hip_bf16.h>
#include <math.h>
#include <cstdint>

#define S_LEN 2048
#define DKH 64

typedef __attribute__((ext_vector_type(8))) short s16x8;
typedef __attribute__((ext_vector_type(4))) float f32x4;

__device__ __forceinline__ unsigned short f2bf(float f) {
  unsigned int u = __float_as_uint(f);
  return (unsigned short)((u + 0x7fffu + ((u >> 16) & 1u)) >> 16);
}

// async global->LDS, 16B per lane, wave-uniform LDS base
__device__ __forceinline__ void glds16(const void* g, void* l) {
  __builtin_amdgcn_global_load_lds(
      (const __attribute__((address_space(1))) unsigned int*)(uintptr_t)g,
      (__attribute__((address_space(3))) unsigned int*)(uintptr_t)l, 16, 0, 0);
}

// ---------------- prep: rope table ----------------
__global__ void k_rope_table(float* __restrict__ cosT, float* __restrict__ sinT) {
  int idx = blockIdx.x * 256 + threadIdx.x;  // 2048*32
  if (idx >= S_LEN * 32) return;
  int s = idx >> 5, i = idx & 31;
  float theta = powf(10000.0f, -(float)i / 32.0f);
  float ang = (float)s * theta;
  float sv, cv;
  sincosf(ang, &sv, &cv);
  cosT[idx] = cv;
  sinT[idx] = sv;
}

// ---------------- prep: 4x weight transpose f32[1024][1024] -> bf16 WT[n][k] ----------------
__global__ __launch_bounds__(256) void k_wtrans4(const float* __restrict__ W0,
                                                 const float* __restrict__ W1,
                                                 const float* __restrict__ W2,
                                                 const float* __restrict__ W3,
                                                 unsigned short* __restrict__ WT) {
  __shared__ float t[32][33];
  const float* W = blockIdx.z == 0 ? W0 : (blockIdx.z == 1 ? W1 : (blockIdx.z == 2 ? W2 : W3));
  unsigned short* dst = WT + (size_t)blockIdx.z * 1048576;
  int n0 = blockIdx.x * 32, k0 = blockIdx.y * 32;
  int tx = threadIdx.x & 31, ty = threadIdx.x >> 5;
#pragma unroll
  for (int p = 0; p < 4; ++p)
    t[ty + p * 8][tx] = W[(size_t)(k0 + ty + p * 8) * 1024 + n0 + tx];
  __syncthreads();
#pragma unroll
  for (int p = 0; p < 4; ++p)
    dst[(size_t)(n0 + ty + p * 8) * 1024 + k0 + tx] = f2bf(t[tx][ty + p * 8]);
}

// ---------------- prep: Q f32 -> bf16 ----------------
__global__ __launch_bounds__(256) void k_qconv(const float* __restrict__ Q,
                                               unsigned short* __restrict__ Qbf) {
  int idx = (blockIdx.x * 256 + threadIdx.x) * 8;
  float4 a = *(const float4*)(Q + idx);
  float4 b = *(const float4*)(Q + idx + 4);
  s16x8 o;
  o[0] = (short)f2bf(a.x); o[1] = (short)f2bf(a.y); o[2] = (short)f2bf(a.z); o[3] = (short)f2bf(a.w);
  o[4] = (short)f2bf(b.x); o[5] = (short)f2bf(b.y); o[6] = (short)f2bf(b.z); o[7] = (short)f2bf(b.w);
  *(s16x8*)(Qbf + idx) = o;
}

// ---------------- prep: v transpose  vl[bh][s][d] -> vt[bh][d][s] (bf16) ----------------
__global__ __launch_bounds__(256) void k_vtrans(const unsigned short* __restrict__ vl,
                                                unsigned short* __restrict__ vt) {
  __shared__ unsigned short t[64][65];
  int bh = blockIdx.y;
  int s0 = blockIdx.x * 64;
  int tx = threadIdx.x & 3;
  int r = threadIdx.x >> 2;
  const unsigned short* src = vl + (size_t)bh * S_LEN * DKH + (size_t)s0 * DKH;
  s16x8 a = *(const s16x8*)(src + r * 64 + tx * 16);
  s16x8 b = *(const s16x8*)(src + r * 64 + tx * 16 + 8);
#pragma unroll
  for (int j = 0; j < 8; ++j) { t[r][tx * 16 + j] = (unsigned short)a[j]; t[r][tx * 16 + 8 + j] = (unsigned short)b[j]; }
  __syncthreads();
  unsigned short* dst = vt + (size_t)bh * DKH * S_LEN + (size_t)r * S_LEN + s0;
  s16x8 o0, o1;
#pragma unroll
  for (int j = 0; j < 8; ++j) { o0[j] = (short)t[tx * 16 + j][r]; o1[j] = (short)t[tx * 16 + 8 + j][r]; }
  *(s16x8*)(dst + tx * 16) = o0;
  *(s16x8*)(dst + tx * 16 + 8) = o1;
}

// ---------------- QKV projection GEMM (m97-style) + bias + RoPE ----------------
__global__ __launch_bounds__(256) void k_qkv(
    const unsigned short* __restrict__ Qbf, const unsigned short* __restrict__ WTqkv,
    const float* __restrict__ bq, const float* __restrict__ bk, const float* __restrict__ bv,
    const float* __restrict__ cosT, const float* __restrict__ sinT,
    unsigned short* __restrict__ ql, unsigned short* __restrict__ kl,
    unsigned short* __restrict__ vl) {
  __shared__ unsigned short As[128 * 64];
  __shared__ unsigned short Bs[128 * 64];
  const int m0 = blockIdx.y * 128, n0 = blockIdx.x * 128;
  const int tid = threadIdx.x, lane = tid & 63, wave = tid >> 6;
  const int wm = (wave >> 1) * 64, wn = (wave & 1) * 64;
  const int lr = lane & 15, lg = lane >> 4;
  const int widx = n0 >> 10;  // 0=q 1=k 2=v
  const float* bias = widx == 0 ? bq : (widx == 1 ? bk : bv);
  const int lrow = lane >> 3, lcol = (lane & 7) * 8;

  f32x4 acc[4][4] = {};
  for (int k0 = 0; k0 < 1024; k0 += 64) {
    __syncthreads();
#pragma unroll
    for (int i = 0; i < 4; ++i) {
      int chunk = wave * 4 + i;
      glds16(Qbf + (size_t)(m0 + 8 * chunk + lrow) * 1024 + k0 + lcol, &As[chunk * 512]);
      glds16(WTqkv + (size_t)(n0 + 8 * chunk + lrow) * 1024 + k0 + lcol, &Bs[chunk * 512]);
    }
    __syncthreads();
#pragma unroll
    for (int ks = 0; ks < 2; ++ks) {
      s16x8 af[4], bf[4];
#pragma unroll
      for (int i = 0; i < 4; ++i) af[i] = *(const s16x8*)&As[(wm + i * 16 + lr) * 64 + ks * 32 + lg * 8];
#pragma unroll
      for (int i = 0; i < 4; ++i) bf[i] = *(const s16x8*)&Bs[(wn + i * 16 + lr) * 64 + ks * 32 + lg * 8];
#pragma unroll
      for (int mi = 0; mi < 4; ++mi)
#pragma unroll
        for (int ni = 0; ni < 4; ++ni)
          acc[mi][ni] = __builtin_amdgcn_mfma_f32_16x16x32_bf16(af[mi], bf[ni], acc[mi][ni], 0, 0, 0);
    }
  }

#pragma unroll
  for (int ni = 0; ni < 4; ++ni) {
    int n = n0 + wn + ni * 16 + lr;
    int np = n & 1023;
    float bval = bias[np];
    int h = np >> 6, d = np & 63;
    int ia = d >> 1;
#pragma unroll
    for (int mi = 0; mi < 4; ++mi) {
#pragma unroll
      for (int r = 0; r < 4; ++r) {
        int m = m0 + wm + mi * 16 + lg * 4 + r;
        int s = m & 2047, b = m >> 11;
        float val = acc[mi][ni][r] + bval;
        size_t oidx = ((size_t)(b * 16 + h) * 2048 + s) * 64 + d;
        if (widx == 2) {
          vl[oidx] = f2bf(val);
        } else {
          float part = __shfl_xor(val, 1);
          float c = cosT[s * 32 + ia], sn = sinT[s * 32 + ia];
          float outv = (d & 1) ? (val * c + part * sn) : (val * c - part * sn);
          (widx == 0 ? ql : kl)[oidx] = f2bf(outv);
        }
      }
    }
  }
}

// ---------------- fused attention: barrier-free hybrid (K/V from L2, prev via LDS dbuf) ----------------
// Per tile t, strict FIFO issue: [K] 8 kf loads (L2) -> [Gp] 4 glds16 prev(t+1)->Pv[buf^1]
// -> QK^T (waits K => drains Gp(t-1) => Pv[buf] ready; Gp(t) stays in flight)
// -> [V] 8 vf loads (L2) -> combine (prev from LDS, zero vmem wait; NT score stores)
// -> softmax/Ps -> PV (waits V => stores + Gp(t) stay in flight). ZERO barriers.
__global__ __launch_bounds__(256, 4) void k_attn(
    const unsigned short* __restrict__ ql, const unsigned short* __restrict__ kl,
    const unsigned short* __restrict__ vt, const float* __restrict__ prev,
    float* __restrict__ scores, unsigned short* __restrict__ attn_out) {
  __shared__ float Pv[2][64 * 64];           // [buf][q 64][kv 64] f32, wave-private 16-row slices
  __shared__ unsigned short Ps[4][16 * 64];  // per-wave [q16][kv64], 128B rows, swizzled

  // bijective XCD swizzle: each XCD owns 4 bh -> K/V (2MB) L2-resident
  const int bid = blockIdx.x;  // 0..1023
  const int xcd = bid & 7, idx = bid >> 3;
  const int bh = xcd * 4 + (idx >> 5);
  const int qb = idx & 31;

  const int tid = threadIdx.x, lane = tid & 63, wave = tid >> 6;
  const int lr = lane & 15, lg = lane >> 4;
  const int qw = qb * 64 + wave * 16;
  const int pr = lane >> 4, pc = lane & 15;  // prev staging: 4 rows x 16 chunks of 16B

  // hoisted Q fragments (A-operand: row=lr, k=ks*32+lg*8)
  s16x8 qf[2];
#pragma unroll
  for (int ks = 0; ks < 2; ++ks)
    qf[ks] = *(const s16x8*)(ql + ((size_t)bh * S_LEN + qw + lr) * DKH + ks * 32 + lg * 8);

  f32x4 o[4] = {};
  float m_run[4], l_run[4];
#pragma unroll
  for (int r = 0; r < 4; ++r) { m_run[r] = -1e30f; l_run[r] = 0.f; }

  const float scale = 0.125f;
  const unsigned short* kbase = kl + (size_t)bh * S_LEN * DKH;
  const unsigned short* vbase = vt + (size_t)bh * DKH * S_LEN;
  const float* prevB = prev + (size_t)bh * S_LEN * S_LEN;
  float* scoB = scores + (size_t)bh * S_LEN * S_LEN;
  unsigned short* PsW = &Ps[wave][0];

  // prologue: stage prev(0) into Pv[0] (drained by tile-0's K-wait; no explicit wait)
#pragma unroll
  for (int i = 0; i < 4; ++i) {
    const int row = qw + i * 4 + pr;
    glds16(prevB + (size_t)row * S_LEN + pc * 4, &Pv[0][(wave * 16 + i * 4) * 64]);
  }

  for (int t = 0; t < 32; ++t) {
    const int cur = t & 1;
    const int kv0 = t * 64;
    const int kvn = ((t + 1) & 31) * 64;  // wrapped: uniform issue count every iter

    // ---- [K] 8 kf loads from L2 (consumed this tile; auto counted wait)
    s16x8 kf[8];
#pragma unroll
    for (int n = 0; n < 4; ++n)
#pragma unroll
      for (int ks = 0; ks < 2; ++ks)
        kf[n * 2 + ks] =
            *(const s16x8*)(kbase + (size_t)(kv0 + n * 16 + lr) * DKH + ks * 32 + lg * 8);
    __builtin_amdgcn_sched_barrier(0);  // pin K before Gp (FIFO wait math)

    // ---- [Gp] stage prev(t+1) into Pv[buf^1] (fire-and-forget)
#pragma unroll
    for (int i = 0; i < 4; ++i) {
      const int row = qw + i * 4 + pr;
      glds16(prevB + (size_t)row * S_LEN + kvn + pc * 4, &Pv[cur ^ 1][(wave * 16 + i * 4) * 64]);
    }
    __builtin_amdgcn_sched_barrier(0);  // pin Gp before compute

    // ---- QK^T consumes kf (wait drains K + Gp(t-1); Gp(t) newer, stays) — T5
    __builtin_amdgcn_s_setprio(1);
    f32x4 sc[4];
#pragma unroll
    for (int n = 0; n < 4; ++n) {
      f32x4 a = {};
#pragma unroll
      for (int ks = 0; ks < 2; ++ks)
        a = __builtin_amdgcn_mfma_f32_16x16x32_bf16(qf[ks], kf[n * 2 + ks], a, 0, 0, 0);
      sc[n] = a;
    }
    __builtin_amdgcn_s_setprio(0);

    // ---- [V] 8 vf loads from L2 (consumed at PV; covered by combine+softmax)
    s16x8 vf[8];
#pragma unroll
    for (int df = 0; df < 4; ++df)
#pragma unroll
      for (int ks = 0; ks < 2; ++ks)
        vf[df * 2 + ks] =
            *(const s16x8*)(vbase + (size_t)(df * 16 + lr) * S_LEN + kv0 + ks * 32 + lg * 8);
    __builtin_amdgcn_sched_barrier(0);  // pin V before combine (stores must be newer)

    // ---- combine with prev(t) from LDS (zero vmem wait), NT score stores, row max
    const float* PvC = &Pv[cur][wave * 16 * 64];
    float tmax[4] = {-1e30f, -1e30f, -1e30f, -1e30f};
#pragma unroll
    for (int n = 0; n < 4; ++n) {
      const int col = kv0 + n * 16 + lr;
#pragma unroll
      for (int r = 0; r < 4; ++r) {
        float v = sc[n][r] * scale + PvC[(lg * 4 + r) * 64 + n * 16 + lr];
        __builtin_nontemporal_store(v, scoB + (size_t)(qw + lg * 4 + r) * S_LEN + col);
        sc[n][r] = v;
        tmax[r] = fmaxf(tmax[r], v);
      }
    }
#pragma unroll
    for (int mask = 1; mask < 16; mask <<= 1)
#pragma unroll
      for (int r = 0; r < 4; ++r) tmax[r] = fmaxf(tmax[r], __shfl_xor(tmax[r], mask));

    // ---- T13 defer-max: skip rescale when max growth <= 8 (wave-uniform branch)
    bool small = true;
#pragma unroll
    for (int r = 0; r < 4; ++r) small = small && (tmax[r] <= m_run[r] + 8.0f);
    if (!__all(small)) {
#pragma unroll
      for (int r = 0; r < 4; ++r) {
        const float mn = fmaxf(m_run[r], tmax[r]);
        const float al = __expf(m_run[r] - mn);
        m_run[r] = mn;
        l_run[r] *= al;
#pragma unroll
        for (int df = 0; df < 4; ++df) o[df][r] *= al;
      }
    }

    // ---- P = exp(S-m) -> per-wave swizzled Ps (same-wave DS order)
#pragma unroll
    for (int n = 0; n < 4; ++n)
#pragma unroll
      for (int r = 0; r < 4; ++r) {
        const float p = __expf(sc[n][r] - m_run[r]);
        l_run[r] += p;
        const int prow = lg * 4 + r;
        *(unsigned short*)((char*)PsW + prow * 128 +
                           ((n * 32 + lr * 2) ^ ((prow & 7) << 4))) = f2bf(p);
      }

    // ---- PV consumes vf (wait drains V; stores + Gp(t) stay in flight) — T5
    s16x8 pa[2];
#pragma unroll
    for (int ks = 0; ks < 2; ++ks)
      pa[ks] = *(const s16x8*)((const char*)PsW + lr * 128 +
                               ((ks * 64 + lg * 16) ^ ((lr & 7) << 4)));
    __builtin_amdgcn_s_setprio(1);
#pragma unroll
    for (int df = 0; df < 4; ++df)
#pragma unroll
      for (int ks = 0; ks < 2; ++ks)
        o[df] = __builtin_amdgcn_mfma_f32_16x16x32_bf16(pa[ks], vf[df * 2 + ks], o[df], 0, 0, 0);
    __builtin_amdgcn_s_setprio(0);
  }

#pragma unroll
  for (int mask = 1; mask < 16; mask <<= 1)
#pragma unroll
    for (int r = 0; r < 4; ++r) l_run[r] += __shfl_xor(l_run[r], mask);
  float inv[4];
#pragma unroll
  for (int r = 0; r < 4; ++r) inv[r] = 1.0f / l_run[r];

  const int b = bh >> 4, h = bh & 15;
#pragma unroll
  for (int df = 0; df < 4; ++df) {
    const int d = df * 16 + lr;
#pragma unroll
    for (int r = 0; r < 4; ++r) {
      const int row = qw + lg * 4 + r;
      attn_out[((size_t)(b * S_LEN + row)) * 1024 + h * 64 + d] = f2bf(o[df][r] * inv[r]);
    }
  }
}

// ---------------- output projection GEMM: 64x64 tiles, grid 1024 (4 blocks/CU) ----------------
__global__ __launch_bounds__(256) void k_outproj(
    const unsigned short* __restrict__ A, const unsigned short* __restrict__ WoT,
    const float* __restrict__ bo, float* __restrict__ out) {
  __shared__ unsigned short As[64 * 64];
  __shared__ unsigned short Bs[64 * 64];
  const int m0 = blockIdx.y * 64, n0 = blockIdx.x * 64;
  const int tid = threadIdx.x, lane = tid & 63, wave = tid >> 6;
  const int wm = (wave >> 1) * 32, wn = (wave & 1) * 32;
  const int lr = lane & 15, lg = lane >> 4;
  const int lrow = lane >> 3, lcol = (lane & 7) * 8;
  f32x4 acc[2][2] = {};
  for (int k0 = 0; k0 < 1024; k0 += 64) {
    __syncthreads();
#pragma unroll
    for (int i = 0; i < 2; ++i) {
      int chunk = wave * 2 + i;  // 8 chunks of 8 rows
      glds16(A + (size_t)(m0 + 8 * chunk + lrow) * 1024 + k0 + lcol, &As[chunk * 512]);
      glds16(WoT + (size_t)(n0 + 8 * chunk + lrow) * 1024 + k0 + lcol, &Bs[chunk * 512]);
    }
    __syncthreads();
#pragma unroll
    for (int ks = 0; ks < 2; ++ks) {
      s16x8 af[2], bf[2];
#pragma unroll
      for (int i = 0; i < 2; ++i) af[i] = *(const s16x8*)&As[(wm + i * 16 + lr) * 64 + ks * 32 + lg * 8];
#pragma unroll
      for (int i = 0; i < 2; ++i) bf[i] = *(const s16x8*)&Bs[(wn + i * 16 + lr) * 64 + ks * 32 + lg * 8];
#pragma unroll
      for (int mi = 0; mi < 2; ++mi)
#pragma unroll
        for (int ni = 0; ni < 2; ++ni)
          acc[mi][ni] = __builtin_amdgcn_mfma_f32_16x16x32_bf16(af[mi], bf[ni], acc[mi][ni], 0, 0, 0);
    }
  }
#pragma unroll
  for (int ni = 0; ni < 2; ++ni) {
    int n = n0 + wn + ni * 16 + lr;
    float bv = bo[n];
#pragma unroll
    for (int mi = 0; mi < 2; ++mi)
#pragma unroll
      for (int rr = 0; rr < 4; ++rr) {
        int m = m0 + wm + mi * 16 + lg * 4 + rr;
        out[(size_t)m * 1024 + n] = acc[mi][ni][rr] + bv;
      }
  }
}

extern "C" void kernel_launch(void* const* d_in, const int* in_sizes, int n_in,
                              void* d_out, int out_size, void* d_ws, size_t ws_size,
                              hipStream_t stream) {
  const float* Q = (const float*)d_in[0];
  const float* prev = (const float*)d_in[1];
  const float* Wq = (const float*)d_in[2];
  const float* bq = (const float*)d_in[3];
  const float* Wk = (const float*)d_in[4];
  const float* bk = (const float*)d_in[5];
  const float* Wv = (const float*)d_in[6];
  const float* bv = (const float*)d_in[7];
  const float* Wo = (const float*)d_in[8];
  const float* bo = (const float*)d_in[9];

  float* out = (float*)d_out;
  float* scores = out + (size_t)4194304;

  char* ws = (char*)d_ws;
  float* cosT = (float*)ws;
  float* sinT = cosT + 65536;
  unsigned short* WTqkv = (unsigned short*)(ws + 524288);  // [3072][1024], then WoT right after
  unsigned short* WoT = WTqkv + 3145728;                   // [1024][1024]
  unsigned short* ql = WoT + 1048576;                      // [32][2048][64]
  unsigned short* kl = ql + 4194304;
  unsigned short* vl = kl + 4194304;
  unsigned short* vt = vl + 4194304;                       // [32][64][2048]
  unsigned short* attn_out = vt + 4194304;                 // [4096][1024]
  unsigned short* Qbf = attn_out + 4194304;                // [4096][1024]

  k_rope_table<<<256, 256, 0, stream>>>(cosT, sinT);
  k_wtrans4<<<dim3(32, 32, 4), 256, 0, stream>>>(Wq, Wk, Wv, Wo, WTqkv);
  k_qconv<<<2048, 256, 0, stream>>>(Q, Qbf);
  k_qkv<<<dim3(24, 32), 256, 0, stream>>>(Qbf, WTqkv, bq, bk, bv, cosT, sinT, ql, kl, vl);
  k_vtrans<<<dim3(32, 32), 256, 0, stream>>>(vl, vt);
  k_attn<<<1024, 256, 0, stream>>>(ql, kl, vt, prev, scores, attn_out);
  k_outproj<<<dim3(16, 64), 256, 0, stream>>>(attn_out, WoT, bo, out);
}

// Round 16
// 365.724 us; speedup vs baseline: 1.6480x; 1.6480x over previous
//
#include <hip/hip_runtime.h>
#include <hip/hip_bf16.h>
#include <math.h>
#include <cstdint>

#define S_LEN 2048
#define DKH 64

typedef __attribute__((ext_vector_type(8))) short s16x8;
typedef __attribute__((ext_vector_type(4))) float f32x4;

__device__ __forceinline__ unsigned short f2bf(float f) {
  unsigned int u = __float_as_uint(f);
  return (unsigned short)((u + 0x7fffu + ((u >> 16) & 1u)) >> 16);
}

// async global->LDS, 16B per lane, wave-uniform LDS base
__device__ __forceinline__ void glds16(const void* g, void* l) {
  __builtin_amdgcn_global_load_lds(
      (const __attribute__((address_space(1))) unsigned int*)(uintptr_t)g,
      (__attribute__((address_space(3))) unsigned int*)(uintptr_t)l, 16, 0, 0);
}

// ---------------- prep: rope table ----------------
__global__ void k_rope_table(float* __restrict__ cosT, float* __restrict__ sinT) {
  int idx = blockIdx.x * 256 + threadIdx.x;  // 2048*32
  if (idx >= S_LEN * 32) return;
  int s = idx >> 5, i = idx & 31;
  float theta = powf(10000.0f, -(float)i / 32.0f);
  float ang = (float)s * theta;
  float sv, cv;
  sincosf(ang, &sv, &cv);
  cosT[idx] = cv;
  sinT[idx] = sv;
}

// ---------------- prep: 4x weight transpose f32[1024][1024] -> bf16 WT[n][k] ----------------
__global__ __launch_bounds__(256) void k_wtrans4(const float* __restrict__ W0,
                                                 const float* __restrict__ W1,
                                                 const float* __restrict__ W2,
                                                 const float* __restrict__ W3,
                                                 unsigned short* __restrict__ WT) {
  __shared__ float t[32][33];
  const float* W = blockIdx.z == 0 ? W0 : (blockIdx.z == 1 ? W1 : (blockIdx.z == 2 ? W2 : W3));
  unsigned short* dst = WT + (size_t)blockIdx.z * 1048576;
  int n0 = blockIdx.x * 32, k0 = blockIdx.y * 32;
  int tx = threadIdx.x & 31, ty = threadIdx.x >> 5;
#pragma unroll
  for (int p = 0; p < 4; ++p)
    t[ty + p * 8][tx] = W[(size_t)(k0 + ty + p * 8) * 1024 + n0 + tx];
  __syncthreads();
#pragma unroll
  for (int p = 0; p < 4; ++p)
    dst[(size_t)(n0 + ty + p * 8) * 1024 + k0 + tx] = f2bf(t[tx][ty + p * 8]);
}

// ---------------- prep: Q f32 -> bf16 ----------------
__global__ __launch_bounds__(256) void k_qconv(const float* __restrict__ Q,
                                               unsigned short* __restrict__ Qbf) {
  int idx = (blockIdx.x * 256 + threadIdx.x) * 8;
  float4 a = *(const float4*)(Q + idx);
  float4 b = *(const float4*)(Q + idx + 4);
  s16x8 o;
  o[0] = (short)f2bf(a.x); o[1] = (short)f2bf(a.y); o[2] = (short)f2bf(a.z); o[3] = (short)f2bf(a.w);
  o[4] = (short)f2bf(b.x); o[5] = (short)f2bf(b.y); o[6] = (short)f2bf(b.z); o[7] = (short)f2bf(b.w);
  *(s16x8*)(Qbf + idx) = o;
}

// ---------------- prep: v transpose  vl[bh][s][d] -> vt[bh][d][s] (bf16) ----------------
__global__ __launch_bounds__(256) void k_vtrans(const unsigned short* __restrict__ vl,
                                                unsigned short* __restrict__ vt) {
  __shared__ unsigned short t[64][65];
  int bh = blockIdx.y;
  int s0 = blockIdx.x * 64;
  int tx = threadIdx.x & 3;
  int r = threadIdx.x >> 2;
  const unsigned short* src = vl + (size_t)bh * S_LEN * DKH + (size_t)s0 * DKH;
  s16x8 a = *(const s16x8*)(src + r * 64 + tx * 16);
  s16x8 b = *(const s16x8*)(src + r * 64 + tx * 16 + 8);
#pragma unroll
  for (int j = 0; j < 8; ++j) { t[r][tx * 16 + j] = (unsigned short)a[j]; t[r][tx * 16 + 8 + j] = (unsigned short)b[j]; }
  __syncthreads();
  unsigned short* dst = vt + (size_t)bh * DKH * S_LEN + (size_t)r * S_LEN + s0;
  s16x8 o0, o1;
#pragma unroll
  for (int j = 0; j < 8; ++j) { o0[j] = (short)t[tx * 16 + j][r]; o1[j] = (short)t[tx * 16 + 8 + j][r]; }
  *(s16x8*)(dst + tx * 16) = o0;
  *(s16x8*)(dst + tx * 16 + 8) = o1;
}

// ---------------- QKV projection GEMM (m97-style) + bias + RoPE, XCD-swizzled grid ----------------
__global__ __launch_bounds__(256) void k_qkv(
    const unsigned short* __restrict__ Qbf, const unsigned short* __restrict__ WTqkv,
    const float* __restrict__ bq, const float* __restrict__ bk, const float* __restrict__ bv,
    const float* __restrict__ cosT, const float* __restrict__ sinT,
    unsigned short* __restrict__ ql, unsigned short* __restrict__ kl,
    unsigned short* __restrict__ vl) {
  __shared__ unsigned short As[128 * 64];
  __shared__ unsigned short Bs[128 * 64];
  // T1: bijective XCD swizzle (nwg=768, 96/XCD): XCD c owns 4 consecutive m-panels
  const int wgid = (blockIdx.x & 7) * 96 + (blockIdx.x >> 3);
  const int m0 = (wgid / 24) * 128, n0 = (wgid % 24) * 128;
  const int tid = threadIdx.x, lane = tid & 63, wave = tid >> 6;
  const int wm = (wave >> 1) * 64, wn = (wave & 1) * 64;
  const int lr = lane & 15, lg = lane >> 4;
  const int widx = n0 >> 10;  // 0=q 1=k 2=v
  const float* bias = widx == 0 ? bq : (widx == 1 ? bk : bv);
  const int lrow = lane >> 3, lcol = (lane & 7) * 8;

  f32x4 acc[4][4] = {};
  for (int k0 = 0; k0 < 1024; k0 += 64) {
    __syncthreads();
#pragma unroll
    for (int i = 0; i < 4; ++i) {
      int chunk = wave * 4 + i;
      glds16(Qbf + (size_t)(m0 + 8 * chunk + lrow) * 1024 + k0 + lcol, &As[chunk * 512]);
      glds16(WTqkv + (size_t)(n0 + 8 * chunk + lrow) * 1024 + k0 + lcol, &Bs[chunk * 512]);
    }
    __syncthreads();
#pragma unroll
    for (int ks = 0; ks < 2; ++ks) {
      s16x8 af[4], bf[4];
#pragma unroll
      for (int i = 0; i < 4; ++i) af[i] = *(const s16x8*)&As[(wm + i * 16 + lr) * 64 + ks * 32 + lg * 8];
#pragma unroll
      for (int i = 0; i < 4; ++i) bf[i] = *(const s16x8*)&Bs[(wn + i * 16 + lr) * 64 + ks * 32 + lg * 8];
#pragma unroll
      for (int mi = 0; mi < 4; ++mi)
#pragma unroll
        for (int ni = 0; ni < 4; ++ni)
          acc[mi][ni] = __builtin_amdgcn_mfma_f32_16x16x32_bf16(af[mi], bf[ni], acc[mi][ni], 0, 0, 0);
    }
  }

#pragma unroll
  for (int ni = 0; ni < 4; ++ni) {
    int n = n0 + wn + ni * 16 + lr;
    int np = n & 1023;
    float bval = bias[np];
    int h = np >> 6, d = np & 63;
    int ia = d >> 1;
#pragma unroll
    for (int mi = 0; mi < 4; ++mi) {
#pragma unroll
      for (int r = 0; r < 4; ++r) {
        int m = m0 + wm + mi * 16 + lg * 4 + r;
        int s = m & 2047, b = m >> 11;
        float val = acc[mi][ni][r] + bval;
        size_t oidx = ((size_t)(b * 16 + h) * 2048 + s) * 64 + d;
        if (widx == 2) {
          vl[oidx] = f2bf(val);
        } else {
          float part = __shfl_xor(val, 1);
          float c = cosT[s * 32 + ia], sn = sinT[s * 32 + ia];
          float outv = (d & 1) ? (val * c + part * sn) : (val * c - part * sn);
          (widx == 0 ? ql : kl)[oidx] = f2bf(outv);
        }
      }
    }
  }
}

// ---------------- fused attention: r14 structure (FROZEN) ----------------
// Per tile (kv=64): [P] 16 prev loads -> [G] 4 glds16 staging t+1 -> QK^T(LDS)
// -> combine consumes P (auto vmcnt(4): G stays in flight) -> softmax/Ps/PV
// -> [S] 16 NT score stores -> asm vmcnt(16) (drains exactly G) -> raw s_barrier.
__global__ __launch_bounds__(256, 4) void k_attn(
    const unsigned short* __restrict__ ql, const unsigned short* __restrict__ kl,
    const unsigned short* __restrict__ vt, const float* __restrict__ prev,
    float* __restrict__ scores, unsigned short* __restrict__ attn_out) {
  __shared__ unsigned short Ks[2][64 * 64];  // [buf][kv 64][dk 64], 128B rows, XOR-swizzled
  __shared__ unsigned short Vs[2][64 * 64];  // [buf][d 64][kv 64], 128B rows, XOR-swizzled
  __shared__ unsigned short Ps[4][16 * 64];  // per-wave [q16][kv64], 128B rows, swizzled

  // bijective XCD swizzle: each XCD owns 4 bh -> K/V (2MB) L2-resident
  const int bid = blockIdx.x;  // 0..1023
  const int xcd = bid & 7, idx = bid >> 3;
  const int bh = xcd * 4 + (idx >> 5);
  const int qb = idx & 31;

  const int tid = threadIdx.x, lane = tid & 63, wave = tid >> 6;
  const int lr = lane & 15, lg = lane >> 4;
  const int qw = qb * 64 + wave * 16;
  const int kr = lane >> 3, kc = lane & 7;  // staging: 8 rows x 8 chunks of 16B

  // hoisted Q fragments (A-operand: row=lr, k=ks*32+lg*8)
  s16x8 qf[2];
#pragma unroll
  for (int ks = 0; ks < 2; ++ks)
    qf[ks] = *(const s16x8*)(ql + ((size_t)bh * S_LEN + qw + lr) * DKH + ks * 32 + lg * 8);

  f32x4 o[4] = {};
  float m_run[4], l_run[4];
#pragma unroll
  for (int r = 0; r < 4; ++r) { m_run[r] = -1e30f; l_run[r] = 0.f; }

  const float scale = 0.125f;
  const unsigned short* kbase = kl + (size_t)bh * S_LEN * DKH;
  const unsigned short* vbase = vt + (size_t)bh * DKH * S_LEN;
  const float* prevB = prev + (size_t)bh * S_LEN * S_LEN;
  float* scoB = scores + (size_t)bh * S_LEN * S_LEN;
  unsigned short* PsW = &Ps[wave][0];

  // prologue: stage tile 0 into buf 0, full drain, barrier
#pragma unroll
  for (int half = 0; half < 2; ++half) {
    const int rb = wave * 16 + half * 8;
    const int row = rb + kr;
    glds16(kbase + (size_t)row * DKH + ((kc ^ kr) * 8), &Ks[0][rb * 64]);
    glds16(vbase + (size_t)row * S_LEN + ((kc ^ kr) * 8), &Vs[0][rb * 64]);
  }
  asm volatile("s_waitcnt vmcnt(0)" ::: "memory");
  __builtin_amdgcn_s_barrier();

  for (int t = 0; t < 32; ++t) {
    const int cur = t & 1;
    const int kv0 = t * 64;
    const int kvn = ((t + 1) & 31) * 64;  // wrapped: uniform glds count every iter

    // ---- [P] prev loads (NT, scalar; consumed at combine via auto vmcnt(4))
    float pvv[16];
#pragma unroll
    for (int n = 0; n < 4; ++n)
#pragma unroll
      for (int r = 0; r < 4; ++r)
        pvv[n * 4 + r] = __builtin_nontemporal_load(
            prevB + (size_t)(qw + lg * 4 + r) * S_LEN + kv0 + n * 16 + lr);
    __builtin_amdgcn_sched_barrier(0);  // pin P before G (vmcnt count depends on order)

    // ---- [G] stage tile t+1 into buf^1 (4 glds16; in flight until end-of-tile)
#pragma unroll
    for (int half = 0; half < 2; ++half) {
      const int rb = wave * 16 + half * 8;
      const int row = rb + kr;
      glds16(kbase + (size_t)(kvn + row) * DKH + ((kc ^ kr) * 8), &Ks[cur ^ 1][rb * 64]);
      glds16(vbase + (size_t)row * S_LEN + kvn + ((kc ^ kr) * 8), &Vs[cur ^ 1][rb * 64]);
    }
    __builtin_amdgcn_sched_barrier(0);  // pin G before compute

    // ---- QK^T from Ks[cur] (LDS only; covers P/G latency) — T5 priority boost
    __builtin_amdgcn_s_setprio(1);
    f32x4 sc[4];
#pragma unroll
    for (int n = 0; n < 4; ++n) {
      f32x4 a = {};
#pragma unroll
      for (int ks = 0; ks < 2; ++ks) {
        s16x8 kf = *(const s16x8*)((const char*)&Ks[cur][0] + (n * 16 + lr) * 128 +
                                   ((ks * 64 + lg * 16) ^ ((lr & 7) << 4)));
        a = __builtin_amdgcn_mfma_f32_16x16x32_bf16(qf[ks], kf, a, 0, 0, 0);
      }
      sc[n] = a;
    }
    __builtin_amdgcn_s_setprio(0);

    // ---- combine with prev (drains P only), NT-stream scores, row max
    float tmax[4] = {-1e30f, -1e30f, -1e30f, -1e30f};
#pragma unroll
    for (int n = 0; n < 4; ++n) {
      const int col = kv0 + n * 16 + lr;
#pragma unroll
      for (int r = 0; r < 4; ++r) {
        float v = sc[n][r] * scale + pvv[n * 4 + r];
        __builtin_nontemporal_store(v, scoB + (size_t)(qw + lg * 4 + r) * S_LEN + col);
        sc[n][r] = v;
        tmax[r] = fmaxf(tmax[r], v);
      }
    }
#pragma unroll
    for (int mask = 1; mask < 16; mask <<= 1)
#pragma unroll
      for (int r = 0; r < 4; ++r) tmax[r] = fmaxf(tmax[r], __shfl_xor(tmax[r], mask));

    // ---- T13 defer-max: skip rescale when max growth <= 8 (wave-uniform branch)
    bool small = true;
#pragma unroll
    for (int r = 0; r < 4; ++r) small = small && (tmax[r] <= m_run[r] + 8.0f);
    if (!__all(small)) {
#pragma unroll
      for (int r = 0; r < 4; ++r) {
        const float mn = fmaxf(m_run[r], tmax[r]);
        const float al = __expf(m_run[r] - mn);
        m_run[r] = mn;
        l_run[r] *= al;
#pragma unroll
        for (int df = 0; df < 4; ++df) o[df][r] *= al;
      }
    }

    // ---- P = exp(S-m) -> per-wave swizzled Ps (same-wave DS order)
#pragma unroll
    for (int n = 0; n < 4; ++n)
#pragma unroll
      for (int r = 0; r < 4; ++r) {
        const float p = __expf(sc[n][r] - m_run[r]);
        l_run[r] += p;
        const int prow = lg * 4 + r;
        *(unsigned short*)((char*)PsW + prow * 128 +
                           ((n * 32 + lr * 2) ^ ((prow & 7) << 4))) = f2bf(p);
      }

    // ---- PV from Ps + Vs[cur] — T5 priority boost
    s16x8 pa[2];
#pragma unroll
    for (int ks = 0; ks < 2; ++ks)
      pa[ks] = *(const s16x8*)((const char*)PsW + lr * 128 +
                               ((ks * 64 + lg * 16) ^ ((lr & 7) << 4)));
    __builtin_amdgcn_s_setprio(1);
#pragma unroll
    for (int df = 0; df < 4; ++df) {
#pragma unroll
      for (int ks = 0; ks < 2; ++ks) {
        s16x8 vb = *(const s16x8*)((const char*)&Vs[cur][0] + (df * 16 + lr) * 128 +
                                   ((ks * 64 + lg * 16) ^ ((lr & 7) << 4)));
        o[df] = __builtin_amdgcn_mfma_f32_16x16x32_bf16(pa[ks], vb, o[df], 0, 0, 0);
      }
    }
    __builtin_amdgcn_s_setprio(0);

    // ---- counted-vmcnt barrier: newer-than-G = exactly the 16 score stores.
    asm volatile("s_waitcnt vmcnt(16)" ::: "memory");
    __builtin_amdgcn_s_barrier();
  }

#pragma unroll
  for (int mask = 1; mask < 16; mask <<= 1)
#pragma unroll
    for (int r = 0; r < 4; ++r) l_run[r] += __shfl_xor(l_run[r], mask);
  float inv[4];
#pragma unroll
  for (int r = 0; r < 4; ++r) inv[r] = 1.0f / l_run[r];

  const int b = bh >> 4, h = bh & 15;
#pragma unroll
  for (int df = 0; df < 4; ++df) {
    const int d = df * 16 + lr;
#pragma unroll
    for (int r = 0; r < 4; ++r) {
      const int row = qw + lg * 4 + r;
      attn_out[((size_t)(b * S_LEN + row)) * 1024 + h * 64 + d] = f2bf(o[df][r] * inv[r]);
    }
  }
}

// ---------------- output projection GEMM: 64x64 tiles, XCD-swizzled grid ----------------
__global__ __launch_bounds__(256) void k_outproj(
    const unsigned short* __restrict__ A, const unsigned short* __restrict__ WoT,
    const float* __restrict__ bo, float* __restrict__ out) {
  __shared__ unsigned short As[64 * 64];
  __shared__ unsigned short Bs[64 * 64];
  // T1: bijective XCD swizzle (nwg=1024, 128/XCD): XCD c owns 8 consecutive m-panels
  const int wgid = (blockIdx.x & 7) * 128 + (blockIdx.x >> 3);
  const int m0 = (wgid / 16) * 64, n0 = (wgid % 16) * 64;
  const int tid = threadIdx.x, lane = tid & 63, wave = tid >> 6;
  const int wm = (wave >> 1) * 32, wn = (wave & 1) * 32;
  const int lr = lane & 15, lg = lane >> 4;
  const int lrow = lane >> 3, lcol = (lane & 7) * 8;
  f32x4 acc[2][2] = {};
  for (int k0 = 0; k0 < 1024; k0 += 64) {
    __syncthreads();
#pragma unroll
    for (int i = 0; i < 2; ++i) {
      int chunk = wave * 2 + i;  // 8 chunks of 8 rows
      glds16(A + (size_t)(m0 + 8 * chunk + lrow) * 1024 + k0 + lcol, &As[chunk * 512]);
      glds16(WoT + (size_t)(n0 + 8 * chunk + lrow) * 1024 + k0 + lcol, &Bs[chunk * 512]);
    }
    __syncthreads();
#pragma unroll
    for (int ks = 0; ks < 2; ++ks) {
      s16x8 af[2], bf[2];
#pragma unroll
      for (int i = 0; i < 2; ++i) af[i] = *(const s16x8*)&As[(wm + i * 16 + lr) * 64 + ks * 32 + lg * 8];
#pragma unroll
      for (int i = 0; i < 2; ++i) bf[i] = *(const s16x8*)&Bs[(wn + i * 16 + lr) * 64 + ks * 32 + lg * 8];
#pragma unroll
      for (int mi = 0; mi < 2; ++mi)
#pragma unroll
        for (int ni = 0; ni < 2; ++ni)
          acc[mi][ni] = __builtin_amdgcn_mfma_f32_16x16x32_bf16(af[mi], bf[ni], acc[mi][ni], 0, 0, 0);
    }
  }
#pragma unroll
  for (int ni = 0; ni < 2; ++ni) {
    int n = n0 + wn + ni * 16 + lr;
    float bv = bo[n];
#pragma unroll
    for (int mi = 0; mi < 2; ++mi)
#pragma unroll
      for (int rr = 0; rr < 4; ++rr) {
        int m = m0 + wm + mi * 16 + lg * 4 + rr;
        out[(size_t)m * 1024 + n] = acc[mi][ni][rr] + bv;
      }
  }
}

extern "C" void kernel_launch(void* const* d_in, const int* in_sizes, int n_in,
                              void* d_out, int out_size, void* d_ws, size_t ws_size,
                              hipStream_t stream) {
  const float* Q = (const float*)d_in[0];
  const float* prev = (const float*)d_in[1];
  const float* Wq = (const float*)d_in[2];
  const float* bq = (const float*)d_in[3];
  const float* Wk = (const float*)d_in[4];
  const float* bk = (const float*)d_in[5];
  const float* Wv = (const float*)d_in[6];
  const float* bv = (const float*)d_in[7];
  const float* Wo = (const float*)d_in[8];
  const float* bo = (const float*)d_in[9];

  float* out = (float*)d_out;
  float* scores = out + (size_t)4194304;

  char* ws = (char*)d_ws;
  float* cosT = (float*)ws;
  float* sinT = cosT + 65536;
  unsigned short* WTqkv = (unsigned short*)(ws + 524288);  // [3072][1024], then WoT right after
  unsigned short* WoT = WTqkv + 3145728;                   // [1024][1024]
  unsigned short* ql = WoT + 1048576;                      // [32][2048][64]
  unsigned short* kl = ql + 4194304;
  unsigned short* vl = kl + 4194304;
  unsigned short* vt = vl + 4194304;                       // [32][64][2048]
  unsigned short* attn_out = vt + 4194304;                 // [4096][1024]
  unsigned short* Qbf = attn_out + 4194304;                // [4096][1024]

  k_rope_table<<<256, 256, 0, stream>>>(cosT, sinT);
  k_wtrans4<<<dim3(32, 32, 4), 256, 0, stream>>>(Wq, Wk, Wv, Wo, WTqkv);
  k_qconv<<<2048, 256, 0, stream>>>(Q, Qbf);
  k_qkv<<<768, 256, 0, stream>>>(Qbf, WTqkv, bq, bk, bv, cosT, sinT, ql, kl, vl);
  k_vtrans<<<dim3(32, 32), 256, 0, stream>>>(vl, vt);
  k_attn<<<1024, 256, 0, stream>>>(ql, kl, vt, prev, scores, attn_out);
  k_outproj<<<1024, 256, 0, stream>>>(attn_out, WoT, bo, out);
}